// Round 10
// baseline (327.170 us; speedup 1.0000x reference)
//
#include <hip/hip_runtime.h>
#include <hip/hip_bf16.h>
#include <stdint.h>

#define S_LEN 2048
#define EMB   1024
#define NHEAD 16
#define HDIM  64
#define BATCH 2

typedef __bf16 bf16x8 __attribute__((ext_vector_type(8)));
typedef float  f32x4  __attribute__((ext_vector_type(4)));

// async global->LDS, 16B per lane; LDS dest = wave-uniform base + lane*16
__device__ __forceinline__ void gll16(const void* g, void* l) {
  __builtin_amdgcn_global_load_lds(
      (const __attribute__((address_space(1))) void*)g,
      (__attribute__((address_space(3))) void*)l,
      16, 0, 0);
}

// ---------------- kernel 0: fused fp32->bf16 cast + mask tile flags ----------
__global__ void __launch_bounds__(256) cast_mask_kernel(
    const float* __restrict__ s0, const float* __restrict__ s1, const float* __restrict__ s2,
    const float* __restrict__ s3, const float* __restrict__ s4, const float* __restrict__ s5,
    const float* __restrict__ s6,
    __hip_bfloat16* __restrict__ d0, __hip_bfloat16* __restrict__ d1,
    __hip_bfloat16* __restrict__ d2, __hip_bfloat16* __restrict__ d3,
    __hip_bfloat16* __restrict__ d4, __hip_bfloat16* __restrict__ d5,
    __hip_bfloat16* __restrict__ d6,
    const int* __restrict__ mask, unsigned* __restrict__ flags) {
  const int z = blockIdx.y;
  const int t = threadIdx.x;
  if (z == 7) {  // mask tile flags: 64q x 128k tiles
    const int kt = blockIdx.x & 15, qt = (blockIdx.x >> 4) & 31, b = (int)blockIdx.x >> 9;
    const int* base = mask + ((size_t)b * S_LEN + (size_t)qt * 64) * S_LEN + (size_t)kt * 128;
    int ok = 1;
#pragma unroll
    for (int p = 0; p < 8; ++p) {
      int idx = p * 256 + t;
      int row = idx >> 5, c4 = idx & 31;
      const int4 v = *(const int4*)(base + (size_t)row * S_LEN + c4 * 4);
      ok &= (v.x != 0) & (v.y != 0) & (v.z != 0) & (v.w != 0);
    }
    unsigned long long bl = __ballot(ok);
    __shared__ unsigned long long bw[4];
    bw[t >> 6] = bl;
    __syncthreads();
    if (t == 0) {
      unsigned all = ((bw[0] & bw[1] & bw[2] & bw[3]) == ~0ull) ? 1u : 0u;
      flags[((size_t)b * 32 + qt) * 16 + kt] = all;
    }
    return;
  }
  const float* s = (z == 0) ? s0 : (z == 1) ? s1 : (z == 2) ? s2 : (z == 3) ? s3
                 : (z == 4) ? s4 : (z == 5) ? s5 : s6;
  __hip_bfloat16* d = (z == 0) ? d0 : (z == 1) ? d1 : (z == 2) ? d2 : (z == 3) ? d3
                    : (z == 4) ? d4 : (z == 5) ? d5 : d6;
  const int n = (z < 3) ? (BATCH * S_LEN * EMB) : (EMB * EMB);
  const size_t i = ((size_t)blockIdx.x * 256 + t) * 16;
  if (i >= (size_t)n) return;
  __hip_bfloat16 tmp[16];
#pragma unroll
  for (int j = 0; j < 4; ++j) {
    const float4 v = *(const float4*)(s + i + j * 4);
    tmp[j * 4 + 0] = __float2bfloat16(v.x);
    tmp[j * 4 + 1] = __float2bfloat16(v.y);
    tmp[j * 4 + 2] = __float2bfloat16(v.z);
    tmp[j * 4 + 3] = __float2bfloat16(v.w);
  }
  *(bf16x8*)(d + i)     = *(bf16x8*)&tmp[0];
  *(bf16x8*)(d + i + 8) = *(bf16x8*)&tmp[8];
}

// ---------------- kernel 1: QKV GEMM, 128x128, BK=64, XCD-local m-tiles -----
// z=0 -> Q (scale log2e/8, [b,h,s,d]); z=1 -> K ([b,h,s,d]);
// z=2 -> V frag-packed (matches flash PV B-operand layout)
__global__ void __launch_bounds__(256, 2)
gemm_kernel(const __hip_bfloat16* __restrict__ A0, const __hip_bfloat16* __restrict__ A1,
            const __hip_bfloat16* __restrict__ A2,
            const __hip_bfloat16* __restrict__ W0, const __hip_bfloat16* __restrict__ W1,
            const __hip_bfloat16* __restrict__ W2,
            const float* __restrict__ b0, const float* __restrict__ b1,
            const float* __restrict__ b2,
            __hip_bfloat16* __restrict__ O0, __hip_bfloat16* __restrict__ O1,
            __hip_bfloat16* __restrict__ O2) {
  __shared__ __align__(16) __hip_bfloat16 As[128 * 64];
  __shared__ __align__(16) __hip_bfloat16 Bs[128 * 64];

  // XCD-local decode: m-tile index mod 8 == blockIdx%8 (A-tile reuse stays on-XCD)
  const int L = blockIdx.x;
  const int m0 = (L & 31) * 128;
  const int n0 = ((L >> 5) & 7) * 128;
  const int z  = L >> 8;

  const __hip_bfloat16* A  = (z == 0) ? A0 : ((z == 1) ? A1 : A2);
  const __hip_bfloat16* W  = (z == 0) ? W0 : ((z == 1) ? W1 : W2);
  const float* bi          = (z == 0) ? b0 : ((z == 1) ? b1 : b2);
  __hip_bfloat16* O        = (z == 0) ? O0 : ((z == 1) ? O1 : O2);

  const int t = threadIdx.x;
  const int w = t >> 6, lane = t & 63, quad = lane >> 4, l15 = lane & 15;
  const int wr = w >> 1, wc = w & 1;

  f32x4 acc[4][4];
#pragma unroll
  for (int i = 0; i < 4; ++i)
#pragma unroll
    for (int j = 0; j < 4; ++j) acc[i][j] = (f32x4)0.0f;

  const int srow = t >> 3;
  const int scb  = (t & 7) ^ (srow & 7);
  const __hip_bfloat16* Ap = A + (size_t)(m0 + srow) * EMB + (scb << 3);
  const __hip_bfloat16* Wp = W + (size_t)(n0 + srow) * EMB + (scb << 3);

  for (int k0 = 0; k0 < EMB; k0 += 64) {
    __syncthreads();
#pragma unroll
    for (int rnd = 0; rnd < 4; ++rnd) {
      gll16(Ap + (size_t)(rnd * 32) * EMB + k0, &As[(rnd * 256 + (w << 6)) * 8]);
      gll16(Wp + (size_t)(rnd * 32) * EMB + k0, &Bs[(rnd * 256 + (w << 6)) * 8]);
    }
    __syncthreads();

    bf16x8 af[4][2], bfr[4][2];
#pragma unroll
    for (int i = 0; i < 4; ++i) {
      const int ra = wr * 64 + i * 16 + l15;
#pragma unroll
      for (int hh = 0; hh < 2; ++hh)
        af[i][hh] = *(const bf16x8*)&As[ra * 64 + ((((hh << 2) + quad) ^ (l15 & 7)) << 3)];
    }
#pragma unroll
    for (int j = 0; j < 4; ++j) {
      const int rbw = wc * 64 + j * 16 + l15;
#pragma unroll
      for (int hh = 0; hh < 2; ++hh)
        bfr[j][hh] = *(const bf16x8*)&Bs[rbw * 64 + ((((hh << 2) + quad) ^ (l15 & 7)) << 3)];
    }
#pragma unroll
    for (int hh = 0; hh < 2; ++hh)
#pragma unroll
      for (int i = 0; i < 4; ++i)
#pragma unroll
        for (int j = 0; j < 4; ++j)
          acc[i][j] =
              __builtin_amdgcn_mfma_f32_16x16x32_bf16(af[i][hh], bfr[j][hh], acc[i][j], 0, 0, 0);
  }

#pragma unroll
  for (int j = 0; j < 4; ++j) {
    const int ng = n0 + wc * 64 + j * 16 + l15;
    const float bb = bi[ng];
    const int h = ng >> 6, d = ng & 63;
#pragma unroll
    for (int i = 0; i < 4; ++i) {
#pragma unroll
      for (int r = 0; r < 4; ++r) {
        const int mg = m0 + wr * 64 + i * 16 + quad * 4 + r;
        const int b = mg >> 11, s = mg & 2047;
        float v = acc[i][j][r] + bb;
        if (z == 0) {        // Q, pre-scaled by log2e/8 so flash uses raw exp2
          O[(((size_t)b * NHEAD + h) * S_LEN + s) * HDIM + d] =
              __float2bfloat16(v * (0.125f * 1.4426950408889634f));
        } else if (z == 1) { // K
          O[(((size_t)b * NHEAD + h) * S_LEN + s) * HDIM + d] = __float2bfloat16(v);
        } else {             // V frag-packed
          const size_t idx = (size_t)(b * NHEAD + h) * 131072 + (size_t)(s >> 7) * 8192 +
                             (size_t)((((s >> 5) & 3) * 4 + ((s >> 2) & 3)) * 64 + d) * 8 +
                             ((s >> 4) & 1) * 4 + (s & 3);
          O[idx] = __float2bfloat16(v);
        }
      }
    }
  }
}

// ---------------- kernel 3: output projection, 64x128, BK=64, XCD-local -----
__global__ void __launch_bounds__(256, 2)
gemm_o_kernel(const __hip_bfloat16* __restrict__ A, const __hip_bfloat16* __restrict__ W,
              const float* __restrict__ bi, float* __restrict__ O) {
  __shared__ __align__(16) __hip_bfloat16 As[64 * 64];
  __shared__ __align__(16) __hip_bfloat16 Bs[128 * 64];
  const int L = blockIdx.x;
  const int m0 = (L & 63) * 64;    // m-tile mod 8 == XCD
  const int n0 = (L >> 6) * 128;
  const int t = threadIdx.x;
  const int w = t >> 6, lane = t & 63, quad = lane >> 4, l15 = lane & 15;
  const int wr = w >> 1, wc = w & 1;

  f32x4 acc[2][4];
#pragma unroll
  for (int i = 0; i < 2; ++i)
#pragma unroll
    for (int j = 0; j < 4; ++j) acc[i][j] = (f32x4)0.0f;

  const int srow = t >> 3;
  const int scb  = (t & 7) ^ (srow & 7);
  const __hip_bfloat16* Ap = A + (size_t)(m0 + srow) * EMB + (scb << 3);
  const __hip_bfloat16* Wp = W + (size_t)(n0 + srow) * EMB + (scb << 3);

  for (int k0 = 0; k0 < EMB; k0 += 64) {
    __syncthreads();
#pragma unroll
    for (int rnd = 0; rnd < 2; ++rnd)
      gll16(Ap + (size_t)(rnd * 32) * EMB + k0, &As[(rnd * 256 + (w << 6)) * 8]);
#pragma unroll
    for (int rnd = 0; rnd < 4; ++rnd)
      gll16(Wp + (size_t)(rnd * 32) * EMB + k0, &Bs[(rnd * 256 + (w << 6)) * 8]);
    __syncthreads();

    bf16x8 af[2][2], bfr[4][2];
#pragma unroll
    for (int i = 0; i < 2; ++i) {
      const int ra = wr * 32 + i * 16 + l15;
#pragma unroll
      for (int hh = 0; hh < 2; ++hh)
        af[i][hh] = *(const bf16x8*)&As[ra * 64 + ((((hh << 2) + quad) ^ (l15 & 7)) << 3)];
    }
#pragma unroll
    for (int j = 0; j < 4; ++j) {
      const int rbw = wc * 64 + j * 16 + l15;
#pragma unroll
      for (int hh = 0; hh < 2; ++hh)
        bfr[j][hh] = *(const bf16x8*)&Bs[rbw * 64 + ((((hh << 2) + quad) ^ (l15 & 7)) << 3)];
    }
#pragma unroll
    for (int hh = 0; hh < 2; ++hh)
#pragma unroll
      for (int i = 0; i < 2; ++i)
#pragma unroll
        for (int j = 0; j < 4; ++j)
          acc[i][j] =
              __builtin_amdgcn_mfma_f32_16x16x32_bf16(af[i][hh], bfr[j][hh], acc[i][j], 0, 0, 0);
  }

#pragma unroll
  for (int j = 0; j < 4; ++j) {
    const int ng = n0 + wc * 64 + j * 16 + l15;
    const float bb = bi[ng];
#pragma unroll
    for (int i = 0; i < 2; ++i) {
#pragma unroll
      for (int r = 0; r < 4; ++r) {
        const int mg = m0 + wr * 32 + i * 16 + quad * 4 + r;
        O[(size_t)mg * EMB + ng] = acc[i][j][r] + bb;
      }
    }
  }
}

// ---------------- kernel 2: flash attention, split-K wave halves ------------
// R8/R9 base + direct-V retry with the register budget actually available:
// amdgpu_waves_per_eu(4,4) tells the allocator max occupancy is 4 waves/EU
// (truthful: LDS 36.9KB + grid 512 cap residency at 2 blocks/CU = 4/EU), so
// it may use up to 128 VGPRs with ZERO occupancy cost. R6's direct-V spilled
// because the default heuristic pinned at the 64-reg/8-wave tier and spilled
// rather than exceed it; this attribute is the documented fix.
// K stays LDS-staged (R5: direct-K serializes L2 latency, +59%), double-
// buffered with prefetch-before-compute + one __syncthreads per tile (R8).
// V is direct-loaded to vv[2][4] at loop top, consumed at PV ~600cy later ->
// latency hidden under QK+softmax; staged bytes/tile halve (32K->16K), drain
// halves, V LDS round-trip gone. vv address formula HW-verified (R5/R6 pass).
// [Ledger: R1 dbuf+asm -12%; R2 (512,8) reg-split spill; R3 TLP null;
// R5 direct-K +59%; R6 direct-V spill@64; R8 prefetch neutral; R9 dechain
// neutral. Validity gate this round: VGPR_Count MUST be >64 with WRITE_SIZE
// ~8.2MB; VGPR=64 + WRITE ballooning = attribute failed -> revert.]
__global__ void __launch_bounds__(512)
__attribute__((amdgpu_waves_per_eu(4, 4)))
flash_kernel(const __hip_bfloat16* __restrict__ qws, const __hip_bfloat16* __restrict__ kws,
             const __hip_bfloat16* __restrict__ vpk, const int* __restrict__ responses,
             const int* __restrict__ mask, const float* __restrict__ Wm,
             const unsigned* __restrict__ flags, __hip_bfloat16* __restrict__ att) {
  __shared__ __align__(16) unsigned char smem[32768];  // K dbuf: buf0@0, buf1@16K; f32 merge overlay
  __shared__ unsigned char rb[S_LEN];                  // key responses as bytes
  __shared__ float lsm[512];                           // lo-half lsum staging

  float* sm = (float*)smem;  // 32KB f32 merge overlay over both K buffers

  const int t = threadIdx.x;
  const int w = t >> 6, lane = t & 63, quad = lane >> 4, l15 = lane & 15;
  const int L = blockIdx.x;
  const int bh = L & 31;         // bh mod 8 == XCD: all q-tiles of a bh co-locate
  const int qt = L >> 5;
  const int b = bh >> 4, h = bh & 15;
  const int q0 = qt * 128;
  const int wq = w & 3, khalf = w >> 2;

#pragma unroll
  for (int i = 0; i < 4; ++i)
    rb[i * 512 + t] = (unsigned char)responses[b * S_LEN + i * 512 + t];

  // Q fragments: q rows q0+wq*32+qg*16+l15 (B-operand of transposed QK^T)
  const __hip_bfloat16* qbase = qws + ((size_t)bh * S_LEN + q0 + wq * 32) * HDIM;
  bf16x8 qf[2][2];
#pragma unroll
  for (int qg = 0; qg < 2; ++qg)
#pragma unroll
    for (int ks = 0; ks < 2; ++ks)
      qf[qg][ks] =
          *(const bf16x8*)(qbase + (size_t)(qg * 16 + l15) * HDIM + ks * 32 + quad * 8);

  const float c = Wm[h] * (0.0625f * 1.4426950408889634f);  // Wm/16 * log2e
  float A2[2];
#pragma unroll
  for (int qg = 0; qg < 2; ++qg)
    A2[qg] = 2.0f * c * (float)responses[b * S_LEN + q0 + wq * 32 + qg * 16 + l15];

  const __hip_bfloat16* kptr = kws + ((size_t)bh * S_LEN + (t >> 3)) * HDIM +
                               (((t & 7) ^ ((t >> 3) & 7)) << 3);
  const __hip_bfloat16* vb = vpk + (size_t)bh * 131072;  // direct-V base (L2-resident)

  float lsum[2] = {0.f, 0.f};
  f32x4 acc_o[2][4];
#pragma unroll
  for (int qg = 0; qg < 2; ++qg)
#pragma unroll
    for (int dt = 0; dt < 4; ++dt) acc_o[qg][dt] = (f32x4)0.0f;

  // ---- prologue: stage K tile 0 into buffer 0 ------------------------------
  {
    __hip_bfloat16* Kd = (__hip_bfloat16*)smem;
#pragma unroll
    for (int p = 0; p < 2; ++p)
      gll16(kptr + p * 64 * HDIM, &Kd[(p * 512 + (w << 6)) * 8]);
    kptr += 128 * HDIM;
  }
  __syncthreads();  // drains tile-0 K staging; also publishes rb

  for (int kt = 0; kt < S_LEN / 128; ++kt) {
    const int cur = kt & 1;

    // prefetch K tile kt+1 into the other buffer; latency hides under this
    // tile's compute. Branchless: kt=15 prefetch reads valid adjacent
    // workspace and lands in the buffer nobody reads again.
    {
      __hip_bfloat16* Kd = (__hip_bfloat16*)(smem + ((cur ^ 1) << 14));
#pragma unroll
      for (int p = 0; p < 2; ++p)
        gll16(kptr + p * 64 * HDIM, &Kd[(p * 512 + (w << 6)) * 8]);
      kptr += 128 * HDIM;
    }
    const __hip_bfloat16* Ks = (const __hip_bfloat16*)(smem + (cur << 14));

    // direct V loads for THIS tile: issued here, consumed at PV after the
    // whole QK+softmax section -> L2 latency fully hidden. 32 VGPRs, free
    // under the (4,4) budget.
    bf16x8 vv[2][4];
#pragma unroll
    for (int ct2 = 0; ct2 < 2; ++ct2) {
      const int g2 = khalf * 2 + ct2;
#pragma unroll
      for (int dt = 0; dt < 4; ++dt)
        vv[ct2][dt] = *(const bf16x8*)(vb + (size_t)kt * 8192 +
                       ((((g2 << 2) + quad) * 64 + (dt << 4) + l15) << 3));
    }

    const unsigned fl = flags[((size_t)b * 32 + 2 * qt + (wq >> 1)) * 16 + kt];

    bf16x8 pfr[2][2];  // [qg][32-key pair-group]
#pragma unroll
    for (int ct = 0; ct < 4; ++ct) {
      const int rowk = khalf * 64 + ct * 16 + l15;
      bf16x8 kf0 = *(const bf16x8*)&Ks[rowk * 64 + ((quad ^ (l15 & 7)) << 3)];
      bf16x8 kf1 = *(const bf16x8*)&Ks[rowk * 64 + (((4 + quad) ^ (l15 & 7)) << 3)];
      const unsigned ru = *(const unsigned*)&rb[kt * 128 + khalf * 64 + ct * 16 + quad * 4];
#pragma unroll
      for (int qg = 0; qg < 2; ++qg) {
        f32x4 sc = __builtin_amdgcn_mfma_f32_16x16x32_bf16(kf0, qf[qg][0], (f32x4)0.0f, 0, 0, 0);
        sc = __builtin_amdgcn_mfma_f32_16x16x32_bf16(kf1, qf[qg][1], sc, 0, 0, 0);
        __hip_bfloat16 pb[4];
        float pv[4];  // ephemeral: pairwise lsum tree (R9, neutral-positive)
#pragma unroll
        for (int r = 0; r < 4; ++r) {
          const float rkf = (float)((ru >> (8 * r)) & 255u);
          const float sb = fmaf(rkf, fmaf(-c, rkf, A2[qg]), sc[r]);
          float p = __builtin_amdgcn_exp2f(sb);
          if (!fl) {  // slow path (all-ones mask never takes it)
            int mq = mask[((size_t)b * S_LEN + q0 + wq * 32 + qg * 16 + l15) * S_LEN +
                          kt * 128 + khalf * 64 + ct * 16 + quad * 4 + r];
            p = mq ? p : 0.0f;
          }
          pv[r] = p;
          pb[r] = __float2bfloat16(p);
        }
        lsum[qg] += (pv[0] + pv[1]) + (pv[2] + pv[3]);
        __hip_bfloat16* half = (__hip_bfloat16*)&pfr[qg][ct >> 1] + (ct & 1) * 4;
        half[0] = pb[0]; half[1] = pb[1]; half[2] = pb[2]; half[3] = pb[3];
      }
    }

    // PV: vv already in registers (loaded at loop top, latency long covered)
#pragma unroll
    for (int ct2 = 0; ct2 < 2; ++ct2) {
#pragma unroll
      for (int dt = 0; dt < 4; ++dt) {
#pragma unroll
        for (int qg = 0; qg < 2; ++qg)
          acc_o[qg][dt] = __builtin_amdgcn_mfma_f32_16x16x32_bf16(pfr[qg][ct2], vv[ct2][dt],
                                                                 acc_o[qg][dt], 0, 0, 0);
      }
    }

    // one barrier per tile: drains the K prefetch (landed during compute) and
    // hands the just-read buffer to next iteration's prefetch.
    __syncthreads();
  }

  // ---- merge the two key-halves (exact fp32 adds), normalize, store -------
  // final loop barrier already synced all waves; K-buffer region is free.
  if (khalf == 0) {
#pragma unroll
    for (int qg = 0; qg < 2; ++qg) {
#pragma unroll
      for (int dt = 0; dt < 4; ++dt)
        *(f32x4*)&sm[((((wq << 1) + qg) << 2) + dt) * 256 + lane * 4] = acc_o[qg][dt];
      lsm[((wq << 1) + qg) * 64 + lane] = lsum[qg];
    }
  }
  __syncthreads();
  if (khalf == 1) {
#pragma unroll
    for (int qg = 0; qg < 2; ++qg) {
      lsum[qg] += lsm[((wq << 1) + qg) * 64 + lane];
      lsum[qg] += __shfl_xor(lsum[qg], 16, 64);
      lsum[qg] += __shfl_xor(lsum[qg], 32, 64);
#pragma unroll
      for (int dt = 0; dt < 4; ++dt)
        acc_o[qg][dt] += *(const f32x4*)&sm[((((wq << 1) + qg) << 2) + dt) * 256 + lane * 4];
      float inv[4];
#pragma unroll
      for (int r = 0; r < 4; ++r) inv[r] = 1.0f / __shfl(lsum[qg], quad * 4 + r, 64);
#pragma unroll
      for (int dt = 0; dt < 4; ++dt)
#pragma unroll
        for (int r = 0; r < 4; ++r)
          att[((size_t)b * S_LEN + q0 + wq * 32 + qg * 16 + quad * 4 + r) * EMB +
              h * HDIM + dt * 16 + l15] = __float2bfloat16(acc_o[qg][dt][r] * inv[r]);
    }
  }
}

// ---------------------------------------------------------------------------
extern "C" void kernel_launch(void* const* d_in, const int* in_sizes, int n_in,
                              void* d_out, int out_size, void* d_ws, size_t ws_size,
                              hipStream_t stream) {
  const float* query = (const float*)d_in[0];
  const float* key_  = (const float*)d_in[1];
  const float* value = (const float*)d_in[2];
  const int* responses = (const int*)d_in[3];
  const int* mask      = (const int*)d_in[4];
  const float* Wq = (const float*)d_in[5];
  const float* bq = (const float*)d_in[6];
  const float* Wk = (const float*)d_in[7];
  const float* bk = (const float*)d_in[8];
  const float* Wv = (const float*)d_in[9];
  const float* bv = (const float*)d_in[10];
  const float* Wo = (const float*)d_in[11];
  const float* bo = (const float*)d_in[12];
  const float* Wm = (const float*)d_in[13];
  // d_in[14] (bm): per-row constant under softmax -> exactly cancels; unused.

  __hip_bfloat16* ws = (__hip_bfloat16*)d_ws;
  const size_t NTOK = (size_t)BATCH * S_LEN * EMB;  // 4 Mi elements
  const size_t NW   = (size_t)EMB * EMB;            // 1 Mi elements
  __hip_bfloat16* qcast = ws;
  __hip_bfloat16* kcast = ws + NTOK;
  __hip_bfloat16* vcast = ws + 2 * NTOK;
  __hip_bfloat16* wqb   = ws + 3 * NTOK;
  __hip_bfloat16* wkb   = wqb + NW;
  __hip_bfloat16* wvb   = wqb + 2 * NW;
  __hip_bfloat16* wob   = wqb + 3 * NW;
  __hip_bfloat16* qws   = wqb + 4 * NW;
  __hip_bfloat16* kws   = qws + NTOK;
  __hip_bfloat16* vpk   = qws + 2 * NTOK;
  __hip_bfloat16* att   = qws + 3 * NTOK;
  unsigned* flags       = (unsigned*)(qws + 4 * NTOK);
  float* out            = (float*)d_out;

  cast_mask_kernel<<<dim3(1024, 8), 256, 0, stream>>>(
      query, key_, value, Wq, Wk, Wv, Wo,
      qcast, kcast, vcast, wqb, wkb, wvb, wob, mask, flags);
  gemm_kernel<<<768, 256, 0, stream>>>(qcast, kcast, vcast, wqb, wkb, wvb,
                                       bq, bk, bv, qws, kws, vpk);
  flash_kernel<<<512, 512, 0, stream>>>(qws, kws, vpk, responses, mask,
                                        Wm, flags, att);
  gemm_o_kernel<<<512, 256, 0, stream>>>(att, wob, bo, out);
}

// Round 11
// 241.546 us; speedup vs baseline: 1.3545x; 1.3545x over previous
//
#include <hip/hip_runtime.h>
#include <hip/hip_bf16.h>
#include <stdint.h>

#define S_LEN 2048
#define EMB   1024
#define NHEAD 16
#define HDIM  64
#define BATCH 2

typedef __bf16 bf16x8 __attribute__((ext_vector_type(8)));
typedef float  f32x4  __attribute__((ext_vector_type(4)));

// async global->LDS, 16B per lane; LDS dest = wave-uniform base + lane*16
__device__ __forceinline__ void gll16(const void* g, void* l) {
  __builtin_amdgcn_global_load_lds(
      (const __attribute__((address_space(1))) void*)g,
      (__attribute__((address_space(3))) void*)l,
      16, 0, 0);
}

// ---------------- kernel 0: fused fp32->bf16 cast + mask tile flags ----------
__global__ void __launch_bounds__(256) cast_mask_kernel(
    const float* __restrict__ s0, const float* __restrict__ s1, const float* __restrict__ s2,
    const float* __restrict__ s3, const float* __restrict__ s4, const float* __restrict__ s5,
    const float* __restrict__ s6,
    __hip_bfloat16* __restrict__ d0, __hip_bfloat16* __restrict__ d1,
    __hip_bfloat16* __restrict__ d2, __hip_bfloat16* __restrict__ d3,
    __hip_bfloat16* __restrict__ d4, __hip_bfloat16* __restrict__ d5,
    __hip_bfloat16* __restrict__ d6,
    const int* __restrict__ mask, unsigned* __restrict__ flags) {
  const int z = blockIdx.y;
  const int t = threadIdx.x;
  if (z == 7) {  // mask tile flags: 64q x 128k tiles
    const int kt = blockIdx.x & 15, qt = (blockIdx.x >> 4) & 31, b = (int)blockIdx.x >> 9;
    const int* base = mask + ((size_t)b * S_LEN + (size_t)qt * 64) * S_LEN + (size_t)kt * 128;
    int ok = 1;
#pragma unroll
    for (int p = 0; p < 8; ++p) {
      int idx = p * 256 + t;
      int row = idx >> 5, c4 = idx & 31;
      const int4 v = *(const int4*)(base + (size_t)row * S_LEN + c4 * 4);
      ok &= (v.x != 0) & (v.y != 0) & (v.z != 0) & (v.w != 0);
    }
    unsigned long long bl = __ballot(ok);
    __shared__ unsigned long long bw[4];
    bw[t >> 6] = bl;
    __syncthreads();
    if (t == 0) {
      unsigned all = ((bw[0] & bw[1] & bw[2] & bw[3]) == ~0ull) ? 1u : 0u;
      flags[((size_t)b * 32 + qt) * 16 + kt] = all;
    }
    return;
  }
  const float* s = (z == 0) ? s0 : (z == 1) ? s1 : (z == 2) ? s2 : (z == 3) ? s3
                 : (z == 4) ? s4 : (z == 5) ? s5 : s6;
  __hip_bfloat16* d = (z == 0) ? d0 : (z == 1) ? d1 : (z == 2) ? d2 : (z == 3) ? d3
                    : (z == 4) ? d4 : (z == 5) ? d5 : d6;
  const int n = (z < 3) ? (BATCH * S_LEN * EMB) : (EMB * EMB);
  const size_t i = ((size_t)blockIdx.x * 256 + t) * 16;
  if (i >= (size_t)n) return;
  __hip_bfloat16 tmp[16];
#pragma unroll
  for (int j = 0; j < 4; ++j) {
    const float4 v = *(const float4*)(s + i + j * 4);
    tmp[j * 4 + 0] = __float2bfloat16(v.x);
    tmp[j * 4 + 1] = __float2bfloat16(v.y);
    tmp[j * 4 + 2] = __float2bfloat16(v.z);
    tmp[j * 4 + 3] = __float2bfloat16(v.w);
  }
  *(bf16x8*)(d + i)     = *(bf16x8*)&tmp[0];
  *(bf16x8*)(d + i + 8) = *(bf16x8*)&tmp[8];
}

// ---------------- kernel 1: QKV GEMM, 128x128, BK=64, XCD-local m-tiles -----
// z=0 -> Q (scale log2e/8, [b,h,s,d]); z=1 -> K ([b,h,s,d]);
// z=2 -> V frag-packed (matches flash PV B-operand layout)
__global__ void __launch_bounds__(256, 2)
gemm_kernel(const __hip_bfloat16* __restrict__ A0, const __hip_bfloat16* __restrict__ A1,
            const __hip_bfloat16* __restrict__ A2,
            const __hip_bfloat16* __restrict__ W0, const __hip_bfloat16* __restrict__ W1,
            const __hip_bfloat16* __restrict__ W2,
            const float* __restrict__ b0, const float* __restrict__ b1,
            const float* __restrict__ b2,
            __hip_bfloat16* __restrict__ O0, __hip_bfloat16* __restrict__ O1,
            __hip_bfloat16* __restrict__ O2) {
  __shared__ __align__(16) __hip_bfloat16 As[128 * 64];
  __shared__ __align__(16) __hip_bfloat16 Bs[128 * 64];

  // XCD-local decode: m-tile index mod 8 == blockIdx%8 (A-tile reuse stays on-XCD)
  const int L = blockIdx.x;
  const int m0 = (L & 31) * 128;
  const int n0 = ((L >> 5) & 7) * 128;
  const int z  = L >> 8;

  const __hip_bfloat16* A  = (z == 0) ? A0 : ((z == 1) ? A1 : A2);
  const __hip_bfloat16* W  = (z == 0) ? W0 : ((z == 1) ? W1 : W2);
  const float* bi          = (z == 0) ? b0 : ((z == 1) ? b1 : b2);
  __hip_bfloat16* O        = (z == 0) ? O0 : ((z == 1) ? O1 : O2);

  const int t = threadIdx.x;
  const int w = t >> 6, lane = t & 63, quad = lane >> 4, l15 = lane & 15;
  const int wr = w >> 1, wc = w & 1;

  f32x4 acc[4][4];
#pragma unroll
  for (int i = 0; i < 4; ++i)
#pragma unroll
    for (int j = 0; j < 4; ++j) acc[i][j] = (f32x4)0.0f;

  const int srow = t >> 3;
  const int scb  = (t & 7) ^ (srow & 7);
  const __hip_bfloat16* Ap = A + (size_t)(m0 + srow) * EMB + (scb << 3);
  const __hip_bfloat16* Wp = W + (size_t)(n0 + srow) * EMB + (scb << 3);

  for (int k0 = 0; k0 < EMB; k0 += 64) {
    __syncthreads();
#pragma unroll
    for (int rnd = 0; rnd < 4; ++rnd) {
      gll16(Ap + (size_t)(rnd * 32) * EMB + k0, &As[(rnd * 256 + (w << 6)) * 8]);
      gll16(Wp + (size_t)(rnd * 32) * EMB + k0, &Bs[(rnd * 256 + (w << 6)) * 8]);
    }
    __syncthreads();

    bf16x8 af[4][2], bfr[4][2];
#pragma unroll
    for (int i = 0; i < 4; ++i) {
      const int ra = wr * 64 + i * 16 + l15;
#pragma unroll
      for (int hh = 0; hh < 2; ++hh)
        af[i][hh] = *(const bf16x8*)&As[ra * 64 + ((((hh << 2) + quad) ^ (l15 & 7)) << 3)];
    }
#pragma unroll
    for (int j = 0; j < 4; ++j) {
      const int rbw = wc * 64 + j * 16 + l15;
#pragma unroll
      for (int hh = 0; hh < 2; ++hh)
        bfr[j][hh] = *(const bf16x8*)&Bs[rbw * 64 + ((((hh << 2) + quad) ^ (l15 & 7)) << 3)];
    }
#pragma unroll
    for (int hh = 0; hh < 2; ++hh)
#pragma unroll
      for (int i = 0; i < 4; ++i)
#pragma unroll
        for (int j = 0; j < 4; ++j)
          acc[i][j] =
              __builtin_amdgcn_mfma_f32_16x16x32_bf16(af[i][hh], bfr[j][hh], acc[i][j], 0, 0, 0);
  }

#pragma unroll
  for (int j = 0; j < 4; ++j) {
    const int ng = n0 + wc * 64 + j * 16 + l15;
    const float bb = bi[ng];
    const int h = ng >> 6, d = ng & 63;
#pragma unroll
    for (int i = 0; i < 4; ++i) {
#pragma unroll
      for (int r = 0; r < 4; ++r) {
        const int mg = m0 + wr * 64 + i * 16 + quad * 4 + r;
        const int b = mg >> 11, s = mg & 2047;
        float v = acc[i][j][r] + bb;
        if (z == 0) {        // Q, pre-scaled by log2e/8 so flash uses raw exp2
          O[(((size_t)b * NHEAD + h) * S_LEN + s) * HDIM + d] =
              __float2bfloat16(v * (0.125f * 1.4426950408889634f));
        } else if (z == 1) { // K
          O[(((size_t)b * NHEAD + h) * S_LEN + s) * HDIM + d] = __float2bfloat16(v);
        } else {             // V frag-packed
          const size_t idx = (size_t)(b * NHEAD + h) * 131072 + (size_t)(s >> 7) * 8192 +
                             (size_t)((((s >> 5) & 3) * 4 + ((s >> 2) & 3)) * 64 + d) * 8 +
                             ((s >> 4) & 1) * 4 + (s & 3);
          O[idx] = __float2bfloat16(v);
        }
      }
    }
  }
}

// ---------------- kernel 3: output projection, 64x128, BK=64, XCD-local -----
__global__ void __launch_bounds__(256, 2)
gemm_o_kernel(const __hip_bfloat16* __restrict__ A, const __hip_bfloat16* __restrict__ W,
              const float* __restrict__ bi, float* __restrict__ O) {
  __shared__ __align__(16) __hip_bfloat16 As[64 * 64];
  __shared__ __align__(16) __hip_bfloat16 Bs[128 * 64];
  const int L = blockIdx.x;
  const int m0 = (L & 63) * 64;    // m-tile mod 8 == XCD
  const int n0 = (L >> 6) * 128;
  const int t = threadIdx.x;
  const int w = t >> 6, lane = t & 63, quad = lane >> 4, l15 = lane & 15;
  const int wr = w >> 1, wc = w & 1;

  f32x4 acc[2][4];
#pragma unroll
  for (int i = 0; i < 2; ++i)
#pragma unroll
    for (int j = 0; j < 4; ++j) acc[i][j] = (f32x4)0.0f;

  const int srow = t >> 3;
  const int scb  = (t & 7) ^ (srow & 7);
  const __hip_bfloat16* Ap = A + (size_t)(m0 + srow) * EMB + (scb << 3);
  const __hip_bfloat16* Wp = W + (size_t)(n0 + srow) * EMB + (scb << 3);

  for (int k0 = 0; k0 < EMB; k0 += 64) {
    __syncthreads();
#pragma unroll
    for (int rnd = 0; rnd < 2; ++rnd)
      gll16(Ap + (size_t)(rnd * 32) * EMB + k0, &As[(rnd * 256 + (w << 6)) * 8]);
#pragma unroll
    for (int rnd = 0; rnd < 4; ++rnd)
      gll16(Wp + (size_t)(rnd * 32) * EMB + k0, &Bs[(rnd * 256 + (w << 6)) * 8]);
    __syncthreads();

    bf16x8 af[2][2], bfr[4][2];
#pragma unroll
    for (int i = 0; i < 2; ++i) {
      const int ra = wr * 32 + i * 16 + l15;
#pragma unroll
      for (int hh = 0; hh < 2; ++hh)
        af[i][hh] = *(const bf16x8*)&As[ra * 64 + ((((hh << 2) + quad) ^ (l15 & 7)) << 3)];
    }
#pragma unroll
    for (int j = 0; j < 4; ++j) {
      const int rbw = wc * 64 + j * 16 + l15;
#pragma unroll
      for (int hh = 0; hh < 2; ++hh)
        bfr[j][hh] = *(const bf16x8*)&Bs[rbw * 64 + ((((hh << 2) + quad) ^ (l15 & 7)) << 3)];
    }
#pragma unroll
    for (int hh = 0; hh < 2; ++hh)
#pragma unroll
      for (int i = 0; i < 2; ++i)
#pragma unroll
        for (int j = 0; j < 4; ++j)
          acc[i][j] =
              __builtin_amdgcn_mfma_f32_16x16x32_bf16(af[i][hh], bfr[j][hh], acc[i][j], 0, 0, 0);
  }

#pragma unroll
  for (int j = 0; j < 4; ++j) {
    const int ng = n0 + wc * 64 + j * 16 + l15;
    const float bb = bi[ng];
#pragma unroll
    for (int i = 0; i < 2; ++i) {
#pragma unroll
      for (int r = 0; r < 4; ++r) {
        const int mg = m0 + wr * 32 + i * 16 + quad * 4 + r;
        O[(size_t)mg * EMB + ng] = acc[i][j][r] + bb;
      }
    }
  }
}

// ---------------- kernel 2: flash attention, split-K wave halves ------------
// SESSION OPTIMUM (R9 state, flash 56.4-56.6us/dispatch): R8 double-buffered
// K/V staging with prefetch-before-compute + ONE plain __syncthreads per
// tile, plus R9's dechained lsum (pairwise tree, chain 32->4 adds/tile).
// FULL LEDGER (all counter-verified; do not revisit):
//   R1  explicit dbuf + asm vmcnt/raw-barrier/sched_barrier  -> -12% (m141 mode)
//   R2  launch_bounds(512,8)        -> reg-file split, 1.2GB spill, 303us
//   R3  grid 1024 / 4 blk/CU target -> residency stays ~2 blk/CU, null
//   R5  direct-K global->reg        -> serialized per-tile L2 latency, 89us
//   R6  direct-V global->reg        -> spill at 64-VGPR wall, 137us
//   R8  prefetch + 1 barrier/tile   -> neutral (kept: one less barrier)
//   R9  lsum dechain                -> neutral-positive (kept: free)
//   R10 direct-V + amdgpu_waves_per_eu(4,4) -> attribute does NOT lift the
//       64-VGPR allocation wall; spilled again (162MB WRITE), 124us.
// Flash is a stable local optimum at ~56.5us under this compiler's 64-VGPR
// allocation: MfmaUtil ~24, VALUBusy ~48, 2 blk/CU, zero spill.
__global__ void __launch_bounds__(512, 4)
flash_kernel(const __hip_bfloat16* __restrict__ qws, const __hip_bfloat16* __restrict__ kws,
             const __hip_bfloat16* __restrict__ vpk, const int* __restrict__ responses,
             const int* __restrict__ mask, const float* __restrict__ Wm,
             const unsigned* __restrict__ flags, __hip_bfloat16* __restrict__ att) {
  __shared__ __align__(16) unsigned char smem[65536];  // buf0 @0 (Ks)+16K (Vs); buf1 @32K/48K
  __shared__ unsigned char rb[S_LEN];                  // key responses as bytes
  __shared__ float lsm[512];                           // lo-half lsum staging

  float* sm = (float*)smem;  // f32 merge overlay over buffer 0 (32 KB)

  const int t = threadIdx.x;
  const int w = t >> 6, lane = t & 63, quad = lane >> 4, l15 = lane & 15;
  const int L = blockIdx.x;
  const int bh = L & 31;         // bh mod 8 == XCD: all q-tiles of a bh co-locate
  const int qt = L >> 5;
  const int b = bh >> 4, h = bh & 15;
  const int q0 = qt * 128;
  const int wq = w & 3, khalf = w >> 2;

#pragma unroll
  for (int i = 0; i < 4; ++i)
    rb[i * 512 + t] = (unsigned char)responses[b * S_LEN + i * 512 + t];

  // Q fragments: q rows q0+wq*32+qg*16+l15 (B-operand of transposed QK^T)
  const __hip_bfloat16* qbase = qws + ((size_t)bh * S_LEN + q0 + wq * 32) * HDIM;
  bf16x8 qf[2][2];
#pragma unroll
  for (int qg = 0; qg < 2; ++qg)
#pragma unroll
    for (int ks = 0; ks < 2; ++ks)
      qf[qg][ks] =
          *(const bf16x8*)(qbase + (size_t)(qg * 16 + l15) * HDIM + ks * 32 + quad * 8);

  const float c = Wm[h] * (0.0625f * 1.4426950408889634f);  // Wm/16 * log2e
  float A2[2];
#pragma unroll
  for (int qg = 0; qg < 2; ++qg)
    A2[qg] = 2.0f * c * (float)responses[b * S_LEN + q0 + wq * 32 + qg * 16 + l15];

  const __hip_bfloat16* kptr = kws + ((size_t)bh * S_LEN + (t >> 3)) * HDIM +
                               (((t & 7) ^ ((t >> 3) & 7)) << 3);
  const __hip_bfloat16* vptr = vpk + (size_t)bh * 131072 + (size_t)t * 8;

  float lsum[2] = {0.f, 0.f};
  f32x4 acc_o[2][4];
#pragma unroll
  for (int qg = 0; qg < 2; ++qg)
#pragma unroll
    for (int dt = 0; dt < 4; ++dt) acc_o[qg][dt] = (f32x4)0.0f;

  // ---- prologue: stage tile 0 into buffer 0 --------------------------------
  {
    __hip_bfloat16* Kd = (__hip_bfloat16*)smem;
    __hip_bfloat16* Vd = Kd + 8192;  // +16 KB
#pragma unroll
    for (int p = 0; p < 2; ++p) {
      gll16(kptr + p * 64 * HDIM, &Kd[(p * 512 + (w << 6)) * 8]);
      gll16(vptr + p * 4096,      &Vd[(p * 512 + (w << 6)) * 8]);
    }
    kptr += 128 * HDIM;
    vptr += 8192;
  }
  __syncthreads();  // drains tile-0 staging; also publishes rb

  for (int kt = 0; kt < S_LEN / 128; ++kt) {
    const int cur = kt & 1;

    // prefetch tile kt+1 into the other buffer; latency hides under this
    // tile's QK/softmax/PV. Branchless: the kt=15 prefetch reads valid
    // adjacent workspace and lands in the buffer nobody reads again.
    {
      __hip_bfloat16* Kd = (__hip_bfloat16*)(smem + (cur ^ 1) * 32768);
      __hip_bfloat16* Vd = Kd + 8192;
#pragma unroll
      for (int p = 0; p < 2; ++p) {
        gll16(kptr + p * 64 * HDIM, &Kd[(p * 512 + (w << 6)) * 8]);
        gll16(vptr + p * 4096,      &Vd[(p * 512 + (w << 6)) * 8]);
      }
      kptr += 128 * HDIM;
      vptr += 8192;
    }
    const __hip_bfloat16* Ks = (const __hip_bfloat16*)(smem + cur * 32768);
    const __hip_bfloat16* Vs = Ks + 8192;

    const unsigned fl = flags[((size_t)b * 32 + 2 * qt + (wq >> 1)) * 16 + kt];

    bf16x8 pfr[2][2];  // [qg][32-key pair-group]
#pragma unroll
    for (int ct = 0; ct < 4; ++ct) {
      const int rowk = khalf * 64 + ct * 16 + l15;
      bf16x8 kf0 = *(const bf16x8*)&Ks[rowk * 64 + ((quad ^ (l15 & 7)) << 3)];
      bf16x8 kf1 = *(const bf16x8*)&Ks[rowk * 64 + (((4 + quad) ^ (l15 & 7)) << 3)];
      const unsigned ru = *(const unsigned*)&rb[kt * 128 + khalf * 64 + ct * 16 + quad * 4];
#pragma unroll
      for (int qg = 0; qg < 2; ++qg) {
        f32x4 sc = __builtin_amdgcn_mfma_f32_16x16x32_bf16(kf0, qf[qg][0], (f32x4)0.0f, 0, 0, 0);
        sc = __builtin_amdgcn_mfma_f32_16x16x32_bf16(kf1, qf[qg][1], sc, 0, 0, 0);
        __hip_bfloat16 pb[4];
        float pv[4];  // ephemeral: pairwise lsum tree, off the serial chain
#pragma unroll
        for (int r = 0; r < 4; ++r) {
          const float rkf = (float)((ru >> (8 * r)) & 255u);
          const float sb = fmaf(rkf, fmaf(-c, rkf, A2[qg]), sc[r]);
          float p = __builtin_amdgcn_exp2f(sb);
          if (!fl) {  // slow path (all-ones mask never takes it)
            int mq = mask[((size_t)b * S_LEN + q0 + wq * 32 + qg * 16 + l15) * S_LEN +
                          kt * 128 + khalf * 64 + ct * 16 + quad * 4 + r];
            p = mq ? p : 0.0f;
          }
          pv[r] = p;
          pb[r] = __float2bfloat16(p);
        }
        // dechained: 2 parallel adds + 1 combine + 1 chain add (chain 32->4/tile)
        lsum[qg] += (pv[0] + pv[1]) + (pv[2] + pv[3]);
        __hip_bfloat16* half = (__hip_bfloat16*)&pfr[qg][ct >> 1] + (ct & 1) * 4;
        half[0] = pb[0]; half[1] = pb[1]; half[2] = pb[2]; half[3] = pb[3];
      }
    }

    // PV: vv loaded once per (ct2,dt), reused for both q-groups
#pragma unroll
    for (int ct2 = 0; ct2 < 2; ++ct2) {
      const int g2 = khalf * 2 + ct2;
#pragma unroll
      for (int dt = 0; dt < 4; ++dt) {
        bf16x8 vv = *(const bf16x8*)&Vs[(((g2 << 2) + quad) * 64 + (dt << 4) + l15) << 3];
#pragma unroll
        for (int qg = 0; qg < 2; ++qg)
          acc_o[qg][dt] =
              __builtin_amdgcn_mfma_f32_16x16x32_bf16(pfr[qg][ct2], vv, acc_o[qg][dt], 0, 0, 0);
      }
    }

    // one barrier per tile: drains the prefetch (landed during compute) and
    // hands the just-read buffer to next iteration's prefetch.
    __syncthreads();
  }

  // ---- merge the two key-halves (exact fp32 adds), normalize, store -------
  // final loop barrier already synced all waves; all gll16 writes drained.
  if (khalf == 0) {
#pragma unroll
    for (int qg = 0; qg < 2; ++qg) {
#pragma unroll
      for (int dt = 0; dt < 4; ++dt)
        *(f32x4*)&sm[((((wq << 1) + qg) << 2) + dt) * 256 + lane * 4] = acc_o[qg][dt];
      lsm[((wq << 1) + qg) * 64 + lane] = lsum[qg];
    }
  }
  __syncthreads();
  if (khalf == 1) {
#pragma unroll
    for (int qg = 0; qg < 2; ++qg) {
      lsum[qg] += lsm[((wq << 1) + qg) * 64 + lane];
      lsum[qg] += __shfl_xor(lsum[qg], 16, 64);
      lsum[qg] += __shfl_xor(lsum[qg], 32, 64);
#pragma unroll
      for (int dt = 0; dt < 4; ++dt)
        acc_o[qg][dt] += *(const f32x4*)&sm[((((wq << 1) + qg) << 2) + dt) * 256 + lane * 4];
      float inv[4];
#pragma unroll
      for (int r = 0; r < 4; ++r) inv[r] = 1.0f / __shfl(lsum[qg], quad * 4 + r, 64);
#pragma unroll
      for (int dt = 0; dt < 4; ++dt)
#pragma unroll
        for (int r = 0; r < 4; ++r)
          att[((size_t)b * S_LEN + q0 + wq * 32 + qg * 16 + quad * 4 + r) * EMB +
              h * HDIM + dt * 16 + l15] = __float2bfloat16(acc_o[qg][dt][r] * inv[r]);
    }
  }
}

// ---------------------------------------------------------------------------
extern "C" void kernel_launch(void* const* d_in, const int* in_sizes, int n_in,
                              void* d_out, int out_size, void* d_ws, size_t ws_size,
                              hipStream_t stream) {
  const float* query = (const float*)d_in[0];
  const float* key_  = (const float*)d_in[1];
  const float* value = (const float*)d_in[2];
  const int* responses = (const int*)d_in[3];
  const int* mask      = (const int*)d_in[4];
  const float* Wq = (const float*)d_in[5];
  const float* bq = (const float*)d_in[6];
  const float* Wk = (const float*)d_in[7];
  const float* bk = (const float*)d_in[8];
  const float* Wv = (const float*)d_in[9];
  const float* bv = (const float*)d_in[10];
  const float* Wo = (const float*)d_in[11];
  const float* bo = (const float*)d_in[12];
  const float* Wm = (const float*)d_in[13];
  // d_in[14] (bm): per-row constant under softmax -> exactly cancels; unused.

  __hip_bfloat16* ws = (__hip_bfloat16*)d_ws;
  const size_t NTOK = (size_t)BATCH * S_LEN * EMB;  // 4 Mi elements
  const size_t NW   = (size_t)EMB * EMB;            // 1 Mi elements
  __hip_bfloat16* qcast = ws;
  __hip_bfloat16* kcast = ws + NTOK;
  __hip_bfloat16* vcast = ws + 2 * NTOK;
  __hip_bfloat16* wqb   = ws + 3 * NTOK;
  __hip_bfloat16* wkb   = wqb + NW;
  __hip_bfloat16* wvb   = wqb + 2 * NW;
  __hip_bfloat16* wob   = wqb + 3 * NW;
  __hip_bfloat16* qws   = wqb + 4 * NW;
  __hip_bfloat16* kws   = qws + NTOK;
  __hip_bfloat16* vpk   = qws + 2 * NTOK;
  __hip_bfloat16* att   = qws + 3 * NTOK;
  unsigned* flags       = (unsigned*)(qws + 4 * NTOK);
  float* out            = (float*)d_out;

  cast_mask_kernel<<<dim3(1024, 8), 256, 0, stream>>>(
      query, key_, value, Wq, Wk, Wv, Wo,
      qcast, kcast, vcast, wqb, wkb, wvb, wob, mask, flags);
  gemm_kernel<<<768, 256, 0, stream>>>(qcast, kcast, vcast, wqb, wkb, wvb,
                                       bq, bk, bv, qws, kws, vpk);
  flash_kernel<<<512, 512, 0, stream>>>(qws, kws, vpk, responses, mask,
                                        Wm, flags, att);
  gemm_o_kernel<<<512, 256, 0, stream>>>(att, wob, bo, out);
}